// Round 6
// baseline (3860.867 us; speedup 1.0000x reference)
//
#include <hip/hip_runtime.h>

#define NN 10000
#define EE 160000
#define FF 128
#define LL 8
#define BB 64
#define DD 512
#define ND (NN * DD)

typedef unsigned short u16;
typedef __attribute__((ext_vector_type(8))) short short8;
typedef __attribute__((ext_vector_type(8))) _Float16 f16x8;
typedef __attribute__((ext_vector_type(4))) float f32x4;
typedef __attribute__((ext_vector_type(4))) u16 u16x4;

__device__ __forceinline__ u16 f2h(float f) {
  return __builtin_bit_cast(u16, (_Float16)f);
}
__device__ __forceinline__ float h2f(u16 h) {
  return (float)__builtin_bit_cast(_Float16, h);
}

#define GLOAD_LDS16(gp, lp)                                                   \
  __builtin_amdgcn_global_load_lds(                                           \
      (const __attribute__((address_space(1))) void*)(gp),                    \
      (__attribute__((address_space(3))) void*)(lp), 16, 0, 0)

// ---------------- fp32 -> fp16 ----------------
__global__ void k_toh(const float* __restrict__ in, u16* __restrict__ out, int n4) {
  int i = blockIdx.x * 256 + threadIdx.x;
  if (i >= n4) return;
  float4 v = ((const float4*)in)[i];
  u16x4 h;
  h.x = f2h(v.x); h.y = f2h(v.y); h.z = f2h(v.z); h.w = f2h(v.w);
  ((u16x4*)out)[i] = h;
}

// ---------------- weight transpose+convert: W[lay][K][512] -> out[(lay*2048+mat*512+n)*K+k] fp16 ----------------
__global__ void k_convw(const float* __restrict__ W0, const float* __restrict__ W1,
                        const float* __restrict__ W2, const float* __restrict__ W3,
                        int K, u16* __restrict__ out) {
  __shared__ float t[32][33];
  int z = blockIdx.z;
  int lay = z >> 2, mat = z & 3;
  const float* W = ((mat == 0) ? W0 : (mat == 1) ? W1 : (mat == 2) ? W2 : W3) +
                   (size_t)lay * K * 512;
  int n0 = blockIdx.x * 32, k0 = blockIdx.y * 32;
  int tx = threadIdx.x, ty = threadIdx.y;
#pragma unroll
  for (int i = 0; i < 4; ++i)
    t[ty + 8 * i][tx] = W[(size_t)(k0 + ty + 8 * i) * 512 + n0 + tx];
  __syncthreads();
#pragma unroll
  for (int i = 0; i < 4; ++i) {
    int n = n0 + ty + 8 * i;
    float val = t[tx][ty + 8 * i];
    size_t o = ((size_t)lay * 2048 + mat * 512 + n) * K + k0 + tx;
    out[o] = f2h(val);
  }
}

// all-layer bias gather: biasf[l][2048]
__global__ void k_fbias(const float* __restrict__ b0q, const float* __restrict__ b0k,
                        const float* __restrict__ b0v, const float* __restrict__ b0s,
                        const float* __restrict__ bq, const float* __restrict__ bk,
                        const float* __restrict__ bv, const float* __restrict__ bs,
                        float* __restrict__ biasf) {
  int j = blockIdx.x * 256 + threadIdx.x;  // 0..16383
  int l = j >> 11, m = (j >> 9) & 3, c = j & 511;
  const float* p;
  if (l == 0) {
    p = (m == 0) ? b0q : (m == 1) ? b0k : (m == 2) ? b0v : b0s;
  } else {
    const float* base = (m == 0) ? bq : (m == 1) ? bk : (m == 2) ? bv : bs;
    p = base + (size_t)(l - 1) * 512;
  }
  biasf[j] = p[c];
}

// ---------------- fused q|k|v|s GEMM: 128x128 tile, 4 waves, BK=32, double-buffered, 32KB LDS ----------------
__global__ __launch_bounds__(256) void k_gemm(
    const u16* __restrict__ Ag, const u16* __restrict__ Bg,
    const float* __restrict__ biasf,
    u16* __restrict__ oq16, u16* __restrict__ ok16, u16* __restrict__ ov16,
    float* __restrict__ os, int M, int K) {
  __shared__ short8 sA[2][512], sB[2][512];
  const int tid = threadIdx.x;
  const int jt = blockIdx.x, mt = blockIdx.y;
  const int m0 = mt * 128;
  const int mat = jt >> 2;
  const int nbase = (jt & 3) * 128;
  const int K8 = K >> 3;
  const int l = tid & 63;
  const int wr = tid >> 7, wc = (tid >> 6) & 1;
  const int g = l >> 4, li = l & 15;

  // staging: LDS chunk c (row r=c>>2, slot jl=c&3) holds global chunk jl ^ (r&3) ^ ((r>>2)&3)
  const int c0 = tid, c1 = tid + 256;
  const int r0 = c0 >> 2, r1 = c1 >> 2;
  const int j0 = (c0 & 3) ^ (r0 & 3) ^ ((r0 >> 2) & 3);
  const int j1 = (c1 & 3) ^ (r1 & 3) ^ ((r1 >> 2) & 3);
  const int am0 = min(m0 + r0, M - 1), am1 = min(m0 + r1, M - 1);
  const int brow = mat * 512 + nbase;
  const short8* gA = (const short8*)Ag;
  const short8* gB = (const short8*)Bg;
  const size_t a0 = (size_t)am0 * K8 + j0, a1 = (size_t)am1 * K8 + j1;
  const size_t b0 = (size_t)(brow + r0) * K8 + j0, b1 = (size_t)(brow + r1) * K8 + j1;

  const f32x4 zero4 = {0.f, 0.f, 0.f, 0.f};
  f32x4 acc[4][4];
#pragma unroll
  for (int i = 0; i < 4; ++i)
#pragma unroll
    for (int j = 0; j < 4; ++j) acc[i][j] = zero4;

  auto stage = [&](int buf, int kg) {
    GLOAD_LDS16(gA + a0 + kg, &sA[buf][c0]);
    GLOAD_LDS16(gA + a1 + kg, &sA[buf][c1]);
    GLOAD_LDS16(gB + b0 + kg, &sB[buf][c0]);
    GLOAD_LDS16(gB + b1 + kg, &sB[buf][c1]);
  };

  auto compute = [&](int buf) {
    f16x8 fa[4], fb[4];
#pragma unroll
    for (int mi = 0; mi < 4; ++mi) {
      int row = wr * 64 + mi * 16 + li;
      int idx = row * 4 + (g ^ (row & 3) ^ ((row >> 2) & 3));
      fa[mi] = __builtin_bit_cast(f16x8, sA[buf][idx]);
    }
#pragma unroll
    for (int ni = 0; ni < 4; ++ni) {
      int row = wc * 64 + ni * 16 + li;
      int idx = row * 4 + (g ^ (row & 3) ^ ((row >> 2) & 3));
      fb[ni] = __builtin_bit_cast(f16x8, sB[buf][idx]);
    }
#pragma unroll
    for (int mi = 0; mi < 4; ++mi)
#pragma unroll
      for (int ni = 0; ni < 4; ++ni)
        acc[mi][ni] = __builtin_amdgcn_mfma_f32_16x16x32_f16(fa[mi], fb[ni], acc[mi][ni], 0, 0, 0);
  };

  int buf = 0;
  stage(0, 0);
  __syncthreads();
  for (int kg = 4; kg < K8; kg += 4) {
    stage(buf ^ 1, kg);   // prefetch next tile; lands during compute
    compute(buf);
    __syncthreads();      // single barrier per K-step (drains vmcnt + joins)
    buf ^= 1;
  }
  compute(buf);

#pragma unroll
  for (int mi = 0; mi < 4; ++mi) {
    int rbase = m0 + wr * 64 + mi * 16 + g * 4;
#pragma unroll
    for (int ni = 0; ni < 4; ++ni) {
      int col = nbase + wc * 64 + ni * 16 + li;
      float bv = biasf[(jt << 7) + wc * 64 + ni * 16 + li];
#pragma unroll
      for (int r = 0; r < 4; ++r) {
        int gm = rbase + r;
        if (gm < M) {
          float val = acc[mi][ni][r] + bv;
          size_t o = (size_t)gm * 512 + col;
          if (mat == 0) oq16[o] = f2h(val);
          else if (mat == 1) ok16[o] = f2h(val);
          else if (mat == 2) ov16[o] = f2h(val);
          else os[o] = val;
        }
      }
    }
  }
}

// ---------------- CSR build ----------------
__global__ void k_count(const int* __restrict__ dst, int* __restrict__ counts) {
  int e = blockIdx.x * 256 + threadIdx.x;
  if (e < EE) atomicAdd(&counts[dst[e]], 1);
}

// 1024 threads, 10 elements each, ~20 barriers total
__global__ void k_scan(const int* __restrict__ counts, int* __restrict__ offs) {
  __shared__ int ws[1024];
  int t = threadIdx.x;
  int base = t * 10;
  int loc[10];
  int run = 0;
#pragma unroll
  for (int j = 0; j < 10; ++j) {
    int i = base + j;
    int v = (i < NN) ? counts[i] : 0;
    run += v;
    loc[j] = run;
  }
  ws[t] = run;
  __syncthreads();
  for (int d = 1; d < 1024; d <<= 1) {
    int x = (t >= d) ? ws[t - d] : 0;
    __syncthreads();
    ws[t] += x;
    __syncthreads();
  }
  int pre = (t > 0) ? ws[t - 1] : 0;
#pragma unroll
  for (int j = 0; j < 10; ++j) {
    int i = base + j;
    if (i < NN) offs[i + 1] = pre + loc[j];
  }
  if (t == 0) offs[0] = 0;
}

__global__ void k_scatter(const int* __restrict__ src, const int* __restrict__ dst,
                          const int* __restrict__ offs, int* __restrict__ cursor,
                          int* __restrict__ esrc) {
  int e = blockIdx.x * 256 + threadIdx.x;
  if (e < EE) {
    int d = dst[e];
    int pos = offs[d] + atomicAdd(&cursor[d], 1);
    esrc[pos] = src[e];
  }
}

__global__ void k_bstart(const int* __restrict__ batch, int* __restrict__ bstart) {
  int n = blockIdx.x * 256 + threadIdx.x;
  if (n > NN) return;
  if (n == 0) {
    for (int b = 0; b <= batch[0]; ++b) bstart[b] = 0;
  } else if (n == NN) {
    for (int b = batch[NN - 1] + 1; b <= BB; ++b) bstart[b] = NN;
  } else {
    int bp = batch[n - 1], bn = batch[n];
    for (int b = bp + 1; b <= bn; ++b) bstart[b] = n;
  }
}

__global__ void k_binv(const int* __restrict__ bstart, float* __restrict__ cinv) {
  int b = threadIdx.x;
  if (b < BB) {
    int c = bstart[b + 1] - bstart[b];
    cinv[b] = 1.f / fmaxf((float)c, 1.f);
  }
}

// ---------------- per-node flash attention (fp16 q/k/v, unroll-2) ----------------
__device__ __forceinline__ void h8tof(short8 x, float* f) {
  f16x8 h = __builtin_bit_cast(f16x8, x);
#pragma unroll
  for (int j = 0; j < 8; ++j) f[j] = (float)h[j];
}

__global__ __launch_bounds__(256) void k_attn(
    const u16* __restrict__ q16, const u16* __restrict__ k16,
    const u16* __restrict__ v16, float* __restrict__ s,
    const int* __restrict__ offs, const int* __restrict__ esrc) {
  int node = blockIdx.x * 4 + (threadIdx.x >> 6);
  int l = threadIdx.x & 63;
  const short8* qp = (const short8*)q16;
  float qf[8];
  h8tof(qp[(size_t)node * 64 + l], qf);
  const short8* kp = (const short8*)k16;
  const short8* vp = (const short8*)v16;
  float m = -3.4e38f, ssum = 0.f;
  float a[8] = {0.f, 0.f, 0.f, 0.f, 0.f, 0.f, 0.f, 0.f};
  int e0 = offs[node], e1 = offs[node + 1];
  int e = e0;
  for (; e + 2 <= e1; e += 2) {
    int sn0 = esrc[e], sn1 = esrc[e + 1];
    short8 kk0 = kp[(size_t)sn0 * 64 + l];
    short8 kk1 = kp[(size_t)sn1 * 64 + l];
    short8 vv0 = vp[(size_t)sn0 * 64 + l];
    short8 vv1 = vp[(size_t)sn1 * 64 + l];
    float kf0[8], kf1[8];
    h8tof(kk0, kf0);
    h8tof(kk1, kf1);
    float d0 = 0.f, d1 = 0.f;
#pragma unroll
    for (int j = 0; j < 8; ++j) { d0 += qf[j] * kf0[j]; d1 += qf[j] * kf1[j]; }
    d0 += __shfl_xor(d0, 1); d1 += __shfl_xor(d1, 1);
    d0 += __shfl_xor(d0, 2); d1 += __shfl_xor(d1, 2);
    d0 += __shfl_xor(d0, 4); d1 += __shfl_xor(d1, 4);
    float vf0[8], vf1[8];
    h8tof(vv0, vf0);
    h8tof(vv1, vf1);
    {
      float logit = d0 * 0.125f;
      float mn = fmaxf(m, logit);
      float sc = __expf(m - mn), p = __expf(logit - mn);
      ssum = ssum * sc + p;
#pragma unroll
      for (int j = 0; j < 8; ++j) a[j] = a[j] * sc + p * vf0[j];
      m = mn;
    }
    {
      float logit = d1 * 0.125f;
      float mn = fmaxf(m, logit);
      float sc = __expf(m - mn), p = __expf(logit - mn);
      ssum = ssum * sc + p;
#pragma unroll
      for (int j = 0; j < 8; ++j) a[j] = a[j] * sc + p * vf1[j];
      m = mn;
    }
  }
  if (e < e1) {
    int sn0 = esrc[e];
    short8 kk0 = kp[(size_t)sn0 * 64 + l];
    short8 vv0 = vp[(size_t)sn0 * 64 + l];
    float kf0[8], vf0[8];
    h8tof(kk0, kf0);
    h8tof(vv0, vf0);
    float d0 = 0.f;
#pragma unroll
    for (int j = 0; j < 8; ++j) d0 += qf[j] * kf0[j];
    d0 += __shfl_xor(d0, 1);
    d0 += __shfl_xor(d0, 2);
    d0 += __shfl_xor(d0, 4);
    float logit = d0 * 0.125f;
    float mn = fmaxf(m, logit);
    float sc = __expf(m - mn), p = __expf(logit - mn);
    ssum = ssum * sc + p;
#pragma unroll
    for (int j = 0; j < 8; ++j) a[j] = a[j] * sc + p * vf0[j];
    m = mn;
  }
  float inv = (e1 > e0) ? 1.f / (ssum + 1e-16f) : 0.f;
  float4* sp = (float4*)(s + (size_t)node * 512);
  float4 s0 = sp[l * 2], s1 = sp[l * 2 + 1];
  s0.x += a[0] * inv; s0.y += a[1] * inv; s0.z += a[2] * inv; s0.w += a[3] * inv;
  s1.x += a[4] * inv; s1.y += a[5] * inv; s1.z += a[6] * inv; s1.w += a[7] * inv;
  sp[l * 2] = s0;
  sp[l * 2 + 1] = s1;
}

// ---------------- BatchNorm partial stats: bnpart[64][1024] (no memset, no atomics) ----------------
__global__ void k_bnstat(const float* __restrict__ s, float* __restrict__ bnpart) {
  int c = blockIdx.x * 256 + threadIdx.x;  // 0..511
  float sum = 0.f, sq = 0.f;
  for (int r = blockIdx.y; r < NN; r += 64) {
    float x = s[(size_t)r * 512 + c];
    sum += x;
    sq += x * x;
  }
  bnpart[blockIdx.y * 1024 + c] = sum;
  bnpart[blockIdx.y * 1024 + 512 + c] = sq;
}

// BN(reduce inline)+ReLU -> fp16 activations + atomic pooled-mean into out
__global__ __launch_bounds__(256) void k_bnapply_pool(
    const float* __restrict__ s, const float* __restrict__ bnpart,
    const float* __restrict__ gamma, const float* __restrict__ beta,
    const int* __restrict__ batch, const float* __restrict__ cinv,
    u16* __restrict__ hh, float* __restrict__ out, int layer) {
  __shared__ float sscl[512], sshf[512];
  int tid = threadIdx.x;
  float a0 = 0.f, a1 = 0.f, a2 = 0.f, a3 = 0.f;
  for (int j = 0; j < 64; ++j) {
    const float* p = bnpart + j * 1024;
    a0 += p[tid];        // sum ch tid
    a1 += p[tid + 256];  // sum ch tid+256
    a2 += p[tid + 512];  // sq  ch tid
    a3 += p[tid + 768];  // sq  ch tid+256
  }
  {
    float mu = a0 * (1.f / NN), var = a2 * (1.f / NN) - mu * mu;
    float inv = rsqrtf(var + 1e-5f);
    float scl = gamma[tid] * inv;
    sscl[tid] = scl;
    sshf[tid] = beta[tid] - mu * scl;
  }
  {
    int c = tid + 256;
    float mu = a1 * (1.f / NN), var = a3 * (1.f / NN) - mu * mu;
    float inv = rsqrtf(var + 1e-5f);
    float scl = gamma[c] * inv;
    sscl[c] = scl;
    sshf[c] = beta[c] - mu * scl;
  }
  __syncthreads();
  int i = blockIdx.x * 256 + tid;  // 4-elem group; ND/4 total
  float4 val = ((const float4*)s)[i];
  int c0 = (i & 127) * 4;
  int r = i >> 7;
  float4 rr;
  rr.x = fmaxf(val.x * sscl[c0] + sshf[c0], 0.f);
  rr.y = fmaxf(val.y * sscl[c0 + 1] + sshf[c0 + 1], 0.f);
  rr.z = fmaxf(val.z * sscl[c0 + 2] + sshf[c0 + 2], 0.f);
  rr.w = fmaxf(val.w * sscl[c0 + 3] + sshf[c0 + 3], 0.f);
  u16x4 h;
  h.x = f2h(rr.x); h.y = f2h(rr.y); h.z = f2h(rr.z); h.w = f2h(rr.w);
  ((u16x4*)hh)[i] = h;
  int b = batch[r];
  float wgt = cinv[b];
  float* op = out + (size_t)b * 4096 + layer * 512 + c0;
  atomicAdd(op + 0, rr.x * wgt);
  atomicAdd(op + 1, rr.y * wgt);
  atomicAdd(op + 2, rr.z * wgt);
  atomicAdd(op + 3, rr.w * wgt);
}

// ---------------- host ----------------
extern "C" void kernel_launch(void* const* d_in, const int* in_sizes, int n_in,
                              void* d_out, int out_size, void* d_ws, size_t ws_size,
                              hipStream_t stream) {
  (void)in_sizes; (void)n_in; (void)ws_size;
  const float* x = (const float*)d_in[0];
  const int* ei = (const int*)d_in[1];
  const int* src = ei;
  const int* dst = ei + EE;
  const int* batch = (const int*)d_in[2];
  const float* W0q = (const float*)d_in[3];
  const float* b0q = (const float*)d_in[4];
  const float* W0k = (const float*)d_in[5];
  const float* b0k = (const float*)d_in[6];
  const float* W0v = (const float*)d_in[7];
  const float* b0v = (const float*)d_in[8];
  const float* W0s = (const float*)d_in[9];
  const float* b0s = (const float*)d_in[10];
  const float* Wq = (const float*)d_in[11];
  const float* bq = (const float*)d_in[12];
  const float* Wk = (const float*)d_in[13];
  const float* bk = (const float*)d_in[14];
  const float* Wv = (const float*)d_in[15];
  const float* bv = (const float*)d_in[16];
  const float* Ws = (const float*)d_in[17];
  const float* bs = (const float*)d_in[18];
  const float* gamma = (const float*)d_in[19];
  const float* beta = (const float*)d_in[20];
  float* out = (float*)d_out;

  char* w = (char*)d_ws;
  size_t off = 0;
  auto alloc = [&](size_t bytes) -> void* {
    void* p = w + off;
    off = (off + bytes + 255) & ~(size_t)255;
    return p;
  };
  u16* xh = (u16*)alloc((size_t)NN * FF * 2);
  u16* hh = (u16*)alloc((size_t)ND * 2);
  u16* qb16 = (u16*)alloc((size_t)ND * 2);
  u16* kb16 = (u16*)alloc((size_t)ND * 2);
  u16* vb16 = (u16*)alloc((size_t)ND * 2);
  float* sb = (float*)alloc((size_t)ND * 4);
  u16* wt0 = (u16*)alloc((size_t)4 * 512 * FF * 2);
  u16* wtN = (u16*)alloc((size_t)7 * 4 * 512 * 512 * 2);
  float* biasf = (float*)alloc((size_t)LL * 2048 * 4);
  float* bnpart = (float*)alloc((size_t)64 * 1024 * 4);
  float* cinv = (float*)alloc(BB * 4);
  int* counts = (int*)alloc(NN * 4);
  int* offs = (int*)alloc((NN + 1) * 4);
  int* cursor = (int*)alloc(NN * 4);
  int* esrc = (int*)alloc(EE * 4);
  int* bstart = (int*)alloc((BB + 1) * 4);

  // ---- once-per-launch setup ----
  hipMemsetAsync(counts, 0, NN * 4, stream);
  hipMemsetAsync(cursor, 0, NN * 4, stream);
  hipMemsetAsync(out, 0, (size_t)out_size * 4, stream);
  k_count<<<EE / 256, 256, 0, stream>>>(dst, counts);
  k_scan<<<1, 1024, 0, stream>>>(counts, offs);
  k_scatter<<<EE / 256, 256, 0, stream>>>(src, dst, offs, cursor, esrc);
  k_bstart<<<(NN + 256) / 256, 256, 0, stream>>>(batch, bstart);
  k_binv<<<1, 64, 0, stream>>>(bstart, cinv);
  k_toh<<<(NN * FF / 4) / 256, 256, 0, stream>>>(x, xh, NN * FF / 4);
  k_convw<<<dim3(16, FF / 32, 4), dim3(32, 8), 0, stream>>>(W0q, W0k, W0v, W0s, FF, wt0);
  k_convw<<<dim3(16, 16, 28), dim3(32, 8), 0, stream>>>(Wq, Wk, Wv, Ws, DD, wtN);
  k_fbias<<<64, 256, 0, stream>>>(b0q, b0k, b0v, b0s, bq, bk, bv, bs, biasf);

  for (int layer = 0; layer < LL; ++layer) {
    int K = (layer == 0) ? FF : DD;
    const u16* A = (layer == 0) ? xh : hh;
    const u16* Bm = (layer == 0) ? wt0 : wtN + (size_t)(layer - 1) * 2048 * 512;
    k_gemm<<<dim3(16, 79), 256, 0, stream>>>(A, Bm, biasf + layer * 2048,
                                             qb16, kb16, vb16, sb, NN, K);
    k_attn<<<NN / 4, 256, 0, stream>>>(qb16, kb16, vb16, sb, offs, esrc);
    k_bnstat<<<dim3(2, 64), 256, 0, stream>>>(sb, bnpart);
    k_bnapply_pool<<<(ND / 4) / 256, 256, 0, stream>>>(
        sb, bnpart, gamma + layer * DD, beta + layer * DD, batch, cinv, hh, out, layer);
  }
}

// Round 7
// 1725.906 us; speedup vs baseline: 2.2370x; 2.2370x over previous
//
#include <hip/hip_runtime.h>

#define NN 10000
#define EE 160000
#define FF 128
#define LL 8
#define BB 64
#define DD 512
#define ND (NN * DD)

typedef unsigned short u16;
typedef __attribute__((ext_vector_type(8))) short short8;
typedef __attribute__((ext_vector_type(8))) _Float16 f16x8;
typedef __attribute__((ext_vector_type(4))) float f32x4;
typedef __attribute__((ext_vector_type(4))) u16 u16x4;

__device__ __forceinline__ u16 f2h(float f) {
  return __builtin_bit_cast(u16, (_Float16)f);
}
__device__ __forceinline__ float h2f(u16 h) {
  return (float)__builtin_bit_cast(_Float16, h);
}

#define GLOAD_LDS16(gp, lp)                                                   \
  __builtin_amdgcn_global_load_lds(                                           \
      (const __attribute__((address_space(1))) void*)(gp),                    \
      (__attribute__((address_space(3))) void*)(lp), 16, 0, 0)

// ---------------- fp32 -> fp16 ----------------
__global__ void k_toh(const float* __restrict__ in, u16* __restrict__ out, int n4) {
  int i = blockIdx.x * 256 + threadIdx.x;
  if (i >= n4) return;
  float4 v = ((const float4*)in)[i];
  u16x4 h;
  h.x = f2h(v.x); h.y = f2h(v.y); h.z = f2h(v.z); h.w = f2h(v.w);
  ((u16x4*)out)[i] = h;
}

// ---------------- weight transpose+convert: W[lay][K][512] -> out[(lay*2048+mat*512+n)*K+k] fp16 ----------------
__global__ void k_convw(const float* __restrict__ W0, const float* __restrict__ W1,
                        const float* __restrict__ W2, const float* __restrict__ W3,
                        int K, u16* __restrict__ out) {
  __shared__ float t[32][33];
  int z = blockIdx.z;
  int lay = z >> 2, mat = z & 3;
  const float* W = ((mat == 0) ? W0 : (mat == 1) ? W1 : (mat == 2) ? W2 : W3) +
                   (size_t)lay * K * 512;
  int n0 = blockIdx.x * 32, k0 = blockIdx.y * 32;
  int tx = threadIdx.x, ty = threadIdx.y;
#pragma unroll
  for (int i = 0; i < 4; ++i)
    t[ty + 8 * i][tx] = W[(size_t)(k0 + ty + 8 * i) * 512 + n0 + tx];
  __syncthreads();
#pragma unroll
  for (int i = 0; i < 4; ++i) {
    int n = n0 + ty + 8 * i;
    float val = t[tx][ty + 8 * i];
    size_t o = ((size_t)lay * 2048 + mat * 512 + n) * K + k0 + tx;
    out[o] = f2h(val);
  }
}

// all-layer bias gather: biasf[l][2048]
__global__ void k_fbias(const float* __restrict__ b0q, const float* __restrict__ b0k,
                        const float* __restrict__ b0v, const float* __restrict__ b0s,
                        const float* __restrict__ bq, const float* __restrict__ bk,
                        const float* __restrict__ bv, const float* __restrict__ bs,
                        float* __restrict__ biasf) {
  int j = blockIdx.x * 256 + threadIdx.x;  // 0..16383
  int l = j >> 11, m = (j >> 9) & 3, c = j & 511;
  const float* p;
  if (l == 0) {
    p = (m == 0) ? b0q : (m == 1) ? b0k : (m == 2) ? b0v : b0s;
  } else {
    const float* base = (m == 0) ? bq : (m == 1) ? bk : (m == 2) ? bv : bs;
    p = base + (size_t)(l - 1) * 512;
  }
  biasf[j] = p[c];
}

// ---------------- fused q|k|v|s GEMM: 128x128 tile, 4 waves, BK=32, double-buffered, 32KB LDS ----------------
__global__ __launch_bounds__(256) void k_gemm(
    const u16* __restrict__ Ag, const u16* __restrict__ Bg,
    const float* __restrict__ biasf,
    u16* __restrict__ oq16, u16* __restrict__ ok16, u16* __restrict__ ov16,
    float* __restrict__ os, int M, int K) {
  __shared__ short8 sA[2][512], sB[2][512];
  const int tid = threadIdx.x;
  const int jt = blockIdx.x, mt = blockIdx.y;
  const int m0 = mt * 128;
  const int mat = jt >> 2;
  const int nbase = (jt & 3) * 128;
  const int K8 = K >> 3;
  const int l = tid & 63;
  const int wr = tid >> 7, wc = (tid >> 6) & 1;
  const int g = l >> 4, li = l & 15;

  // staging: LDS chunk c (row r=c>>2, slot jl=c&3) holds global chunk jl ^ (r&3) ^ ((r>>2)&3)
  const int c0 = tid, c1 = tid + 256;
  const int r0 = c0 >> 2, r1 = c1 >> 2;
  const int j0 = (c0 & 3) ^ (r0 & 3) ^ ((r0 >> 2) & 3);
  const int j1 = (c1 & 3) ^ (r1 & 3) ^ ((r1 >> 2) & 3);
  const int am0 = min(m0 + r0, M - 1), am1 = min(m0 + r1, M - 1);
  const int brow = mat * 512 + nbase;
  const short8* gA = (const short8*)Ag;
  const short8* gB = (const short8*)Bg;
  const size_t a0 = (size_t)am0 * K8 + j0, a1 = (size_t)am1 * K8 + j1;
  const size_t b0 = (size_t)(brow + r0) * K8 + j0, b1 = (size_t)(brow + r1) * K8 + j1;

  const f32x4 zero4 = {0.f, 0.f, 0.f, 0.f};
  f32x4 acc[4][4];
#pragma unroll
  for (int i = 0; i < 4; ++i)
#pragma unroll
    for (int j = 0; j < 4; ++j) acc[i][j] = zero4;

  auto stage = [&](int buf, int kg) {
    GLOAD_LDS16(gA + a0 + kg, &sA[buf][c0]);
    GLOAD_LDS16(gA + a1 + kg, &sA[buf][c1]);
    GLOAD_LDS16(gB + b0 + kg, &sB[buf][c0]);
    GLOAD_LDS16(gB + b1 + kg, &sB[buf][c1]);
  };

  auto compute = [&](int buf) {
    f16x8 fa[4], fb[4];
#pragma unroll
    for (int mi = 0; mi < 4; ++mi) {
      int row = wr * 64 + mi * 16 + li;
      int idx = row * 4 + (g ^ (row & 3) ^ ((row >> 2) & 3));
      fa[mi] = __builtin_bit_cast(f16x8, sA[buf][idx]);
    }
#pragma unroll
    for (int ni = 0; ni < 4; ++ni) {
      int row = wc * 64 + ni * 16 + li;
      int idx = row * 4 + (g ^ (row & 3) ^ ((row >> 2) & 3));
      fb[ni] = __builtin_bit_cast(f16x8, sB[buf][idx]);
    }
#pragma unroll
    for (int mi = 0; mi < 4; ++mi)
#pragma unroll
      for (int ni = 0; ni < 4; ++ni)
        acc[mi][ni] = __builtin_amdgcn_mfma_f32_16x16x32_f16(fa[mi], fb[ni], acc[mi][ni], 0, 0, 0);
  };

  int buf = 0;
  stage(0, 0);
  __syncthreads();
  for (int kg = 4; kg < K8; kg += 4) {
    stage(buf ^ 1, kg);   // prefetch next tile; lands during compute
    compute(buf);
    __syncthreads();      // single barrier per K-step (drains vmcnt + joins)
    buf ^= 1;
  }
  compute(buf);

#pragma unroll
  for (int mi = 0; mi < 4; ++mi) {
    int rbase = m0 + wr * 64 + mi * 16 + g * 4;
#pragma unroll
    for (int ni = 0; ni < 4; ++ni) {
      int col = nbase + wc * 64 + ni * 16 + li;
      float bv = biasf[(jt << 7) + wc * 64 + ni * 16 + li];
#pragma unroll
      for (int r = 0; r < 4; ++r) {
        int gm = rbase + r;
        if (gm < M) {
          float val = acc[mi][ni][r] + bv;
          size_t o = (size_t)gm * 512 + col;
          if (mat == 0) oq16[o] = f2h(val);
          else if (mat == 1) ok16[o] = f2h(val);
          else if (mat == 2) ov16[o] = f2h(val);
          else os[o] = val;
        }
      }
    }
  }
}

// ---------------- CSR build ----------------
__global__ void k_count(const int* __restrict__ dst, int* __restrict__ counts) {
  int e = blockIdx.x * 256 + threadIdx.x;
  if (e < EE) atomicAdd(&counts[dst[e]], 1);
}

// 1024 threads, 10 elements each
__global__ void k_scan(const int* __restrict__ counts, int* __restrict__ offs) {
  __shared__ int ws[1024];
  int t = threadIdx.x;
  int base = t * 10;
  int loc[10];
  int run = 0;
#pragma unroll
  for (int j = 0; j < 10; ++j) {
    int i = base + j;
    int v = (i < NN) ? counts[i] : 0;
    run += v;
    loc[j] = run;
  }
  ws[t] = run;
  __syncthreads();
  for (int d = 1; d < 1024; d <<= 1) {
    int x = (t >= d) ? ws[t - d] : 0;
    __syncthreads();
    ws[t] += x;
    __syncthreads();
  }
  int pre = (t > 0) ? ws[t - 1] : 0;
#pragma unroll
  for (int j = 0; j < 10; ++j) {
    int i = base + j;
    if (i < NN) offs[i + 1] = pre + loc[j];
  }
  if (t == 0) offs[0] = 0;
}

__global__ void k_scatter(const int* __restrict__ src, const int* __restrict__ dst,
                          const int* __restrict__ offs, int* __restrict__ cursor,
                          int* __restrict__ esrc) {
  int e = blockIdx.x * 256 + threadIdx.x;
  if (e < EE) {
    int d = dst[e];
    int pos = offs[d] + atomicAdd(&cursor[d], 1);
    esrc[pos] = src[e];
  }
}

__global__ void k_bstart(const int* __restrict__ batch, int* __restrict__ bstart) {
  int n = blockIdx.x * 256 + threadIdx.x;
  if (n > NN) return;
  if (n == 0) {
    for (int b = 0; b <= batch[0]; ++b) bstart[b] = 0;
  } else if (n == NN) {
    for (int b = batch[NN - 1] + 1; b <= BB; ++b) bstart[b] = NN;
  } else {
    int bp = batch[n - 1], bn = batch[n];
    for (int b = bp + 1; b <= bn; ++b) bstart[b] = n;
  }
}

// ---------------- per-node flash attention (fp16 q/k/v, unroll-2) ----------------
__device__ __forceinline__ void h8tof(short8 x, float* f) {
  f16x8 h = __builtin_bit_cast(f16x8, x);
#pragma unroll
  for (int j = 0; j < 8; ++j) f[j] = (float)h[j];
}

__global__ __launch_bounds__(256) void k_attn(
    const u16* __restrict__ q16, const u16* __restrict__ k16,
    const u16* __restrict__ v16, float* __restrict__ s,
    const int* __restrict__ offs, const int* __restrict__ esrc) {
  int node = blockIdx.x * 4 + (threadIdx.x >> 6);
  int l = threadIdx.x & 63;
  const short8* qp = (const short8*)q16;
  float qf[8];
  h8tof(qp[(size_t)node * 64 + l], qf);
  const short8* kp = (const short8*)k16;
  const short8* vp = (const short8*)v16;
  float m = -3.4e38f, ssum = 0.f;
  float a[8] = {0.f, 0.f, 0.f, 0.f, 0.f, 0.f, 0.f, 0.f};
  int e0 = offs[node], e1 = offs[node + 1];
  int e = e0;
  for (; e + 2 <= e1; e += 2) {
    int sn0 = esrc[e], sn1 = esrc[e + 1];
    short8 kk0 = kp[(size_t)sn0 * 64 + l];
    short8 kk1 = kp[(size_t)sn1 * 64 + l];
    short8 vv0 = vp[(size_t)sn0 * 64 + l];
    short8 vv1 = vp[(size_t)sn1 * 64 + l];
    float kf0[8], kf1[8];
    h8tof(kk0, kf0);
    h8tof(kk1, kf1);
    float d0 = 0.f, d1 = 0.f;
#pragma unroll
    for (int j = 0; j < 8; ++j) { d0 += qf[j] * kf0[j]; d1 += qf[j] * kf1[j]; }
    d0 += __shfl_xor(d0, 1); d1 += __shfl_xor(d1, 1);
    d0 += __shfl_xor(d0, 2); d1 += __shfl_xor(d1, 2);
    d0 += __shfl_xor(d0, 4); d1 += __shfl_xor(d1, 4);
    float vf0[8], vf1[8];
    h8tof(vv0, vf0);
    h8tof(vv1, vf1);
    {
      float logit = d0 * 0.125f;
      float mn = fmaxf(m, logit);
      float sc = __expf(m - mn), p = __expf(logit - mn);
      ssum = ssum * sc + p;
#pragma unroll
      for (int j = 0; j < 8; ++j) a[j] = a[j] * sc + p * vf0[j];
      m = mn;
    }
    {
      float logit = d1 * 0.125f;
      float mn = fmaxf(m, logit);
      float sc = __expf(m - mn), p = __expf(logit - mn);
      ssum = ssum * sc + p;
#pragma unroll
      for (int j = 0; j < 8; ++j) a[j] = a[j] * sc + p * vf1[j];
      m = mn;
    }
  }
  if (e < e1) {
    int sn0 = esrc[e];
    short8 kk0 = kp[(size_t)sn0 * 64 + l];
    short8 vv0 = vp[(size_t)sn0 * 64 + l];
    float kf0[8], vf0[8];
    h8tof(kk0, kf0);
    h8tof(vv0, vf0);
    float d0 = 0.f;
#pragma unroll
    for (int j = 0; j < 8; ++j) d0 += qf[j] * kf0[j];
    d0 += __shfl_xor(d0, 1);
    d0 += __shfl_xor(d0, 2);
    d0 += __shfl_xor(d0, 4);
    float logit = d0 * 0.125f;
    float mn = fmaxf(m, logit);
    float sc = __expf(m - mn), p = __expf(logit - mn);
    ssum = ssum * sc + p;
#pragma unroll
    for (int j = 0; j < 8; ++j) a[j] = a[j] * sc + p * vf0[j];
    m = mn;
  }
  float inv = (e1 > e0) ? 1.f / (ssum + 1e-16f) : 0.f;
  float4* sp = (float4*)(s + (size_t)node * 512);
  float4 s0 = sp[l * 2], s1 = sp[l * 2 + 1];
  s0.x += a[0] * inv; s0.y += a[1] * inv; s0.z += a[2] * inv; s0.w += a[3] * inv;
  s1.x += a[4] * inv; s1.y += a[5] * inv; s1.z += a[6] * inv; s1.w += a[7] * inv;
  sp[l * 2] = s0;
  sp[l * 2 + 1] = s1;
}

// ---------------- BatchNorm partial stats: bnpart[64][1024] (no memset, no atomics) ----------------
__global__ void k_bnstat(const float* __restrict__ s, float* __restrict__ bnpart) {
  int c = blockIdx.x * 256 + threadIdx.x;  // 0..511
  float sum = 0.f, sq = 0.f;
  for (int r = blockIdx.y; r < NN; r += 64) {
    float x = s[(size_t)r * 512 + c];
    sum += x;
    sq += x * x;
  }
  bnpart[blockIdx.y * 1024 + c] = sum;
  bnpart[blockIdx.y * 1024 + 512 + c] = sq;
}

// reduce 64 partials -> scale/shift (1 block, 512 threads)
__global__ void k_bnfinal(const float* __restrict__ bnpart, const float* __restrict__ gamma,
                          const float* __restrict__ beta, float* __restrict__ scale,
                          float* __restrict__ shift) {
  int c = threadIdx.x;
  float sum = 0.f, sq = 0.f;
  for (int j = 0; j < 64; ++j) {
    sum += bnpart[j * 1024 + c];
    sq += bnpart[j * 1024 + 512 + c];
  }
  float mu = sum * (1.f / NN);
  float var = sq * (1.f / NN) - mu * mu;
  float inv = rsqrtf(var + 1e-5f);
  float scl = gamma[c] * inv;
  scale[c] = scl;
  shift[c] = beta[c] - mu * scl;
}

// BN+ReLU -> next-layer fp16 activations
__global__ void k_bnapply(const float* __restrict__ s, const float* __restrict__ scale,
                          const float* __restrict__ shift, u16* __restrict__ hh) {
  int i = blockIdx.x * 256 + threadIdx.x;  // 4-elem group
  float4 val = ((const float4*)s)[i];
  int c4 = i & 127;
  float4 scl = ((const float4*)scale)[c4];
  float4 shf = ((const float4*)shift)[c4];
  float4 r;
  r.x = fmaxf(val.x * scl.x + shf.x, 0.f);
  r.y = fmaxf(val.y * scl.y + shf.y, 0.f);
  r.z = fmaxf(val.z * scl.z + shf.z, 0.f);
  r.w = fmaxf(val.w * scl.w + shf.w, 0.f);
  u16x4 h;
  h.x = f2h(r.x); h.y = f2h(r.y); h.z = f2h(r.z); h.w = f2h(r.w);
  ((u16x4*)hh)[i] = h;
}

// pool reads normalized fp16 activations; one plain store per output element
__global__ void k_pool(const u16* __restrict__ hh, const int* __restrict__ bstart,
                       float* __restrict__ out, int layer) {
  int c = blockIdx.x * 256 + threadIdx.x;
  int b = blockIdx.y;
  int r0 = bstart[b], r1 = bstart[b + 1];
  float sum = 0.f;
  for (int r = r0; r < r1; ++r) sum += h2f(hh[(size_t)r * 512 + c]);
  out[b * 4096 + layer * 512 + c] = sum / fmaxf((float)(r1 - r0), 1.f);
}

// ---------------- host ----------------
extern "C" void kernel_launch(void* const* d_in, const int* in_sizes, int n_in,
                              void* d_out, int out_size, void* d_ws, size_t ws_size,
                              hipStream_t stream) {
  (void)in_sizes; (void)n_in; (void)out_size; (void)ws_size;
  const float* x = (const float*)d_in[0];
  const int* ei = (const int*)d_in[1];
  const int* src = ei;
  const int* dst = ei + EE;
  const int* batch = (const int*)d_in[2];
  const float* W0q = (const float*)d_in[3];
  const float* b0q = (const float*)d_in[4];
  const float* W0k = (const float*)d_in[5];
  const float* b0k = (const float*)d_in[6];
  const float* W0v = (const float*)d_in[7];
  const float* b0v = (const float*)d_in[8];
  const float* W0s = (const float*)d_in[9];
  const float* b0s = (const float*)d_in[10];
  const float* Wq = (const float*)d_in[11];
  const float* bq = (const float*)d_in[12];
  const float* Wk = (const float*)d_in[13];
  const float* bk = (const float*)d_in[14];
  const float* Wv = (const float*)d_in[15];
  const float* bv = (const float*)d_in[16];
  const float* Ws = (const float*)d_in[17];
  const float* bs = (const float*)d_in[18];
  const float* gamma = (const float*)d_in[19];
  const float* beta = (const float*)d_in[20];
  float* out = (float*)d_out;

  char* w = (char*)d_ws;
  size_t off = 0;
  auto alloc = [&](size_t bytes) -> void* {
    void* p = w + off;
    off = (off + bytes + 255) & ~(size_t)255;
    return p;
  };
  u16* xh = (u16*)alloc((size_t)NN * FF * 2);
  u16* hh = (u16*)alloc((size_t)ND * 2);
  u16* qb16 = (u16*)alloc((size_t)ND * 2);
  u16* kb16 = (u16*)alloc((size_t)ND * 2);
  u16* vb16 = (u16*)alloc((size_t)ND * 2);
  float* sb = (float*)alloc((size_t)ND * 4);
  u16* wt0 = (u16*)alloc((size_t)4 * 512 * FF * 2);
  u16* wtN = (u16*)alloc((size_t)7 * 4 * 512 * 512 * 2);
  float* biasf = (float*)alloc((size_t)LL * 2048 * 4);
  float* bnpart = (float*)alloc((size_t)64 * 1024 * 4);
  float* bnscale = (float*)alloc(512 * 4);
  float* bnshift = (float*)alloc(512 * 4);
  int* counts = (int*)alloc(NN * 4);
  int* offs = (int*)alloc((NN + 1) * 4);
  int* cursor = (int*)alloc(NN * 4);
  int* esrc = (int*)alloc(EE * 4);
  int* bstart = (int*)alloc((BB + 1) * 4);

  // ---- once-per-launch setup ----
  hipMemsetAsync(counts, 0, NN * 4, stream);
  hipMemsetAsync(cursor, 0, NN * 4, stream);
  k_count<<<EE / 256, 256, 0, stream>>>(dst, counts);
  k_scan<<<1, 1024, 0, stream>>>(counts, offs);
  k_scatter<<<EE / 256, 256, 0, stream>>>(src, dst, offs, cursor, esrc);
  k_bstart<<<(NN + 256) / 256, 256, 0, stream>>>(batch, bstart);
  k_toh<<<(NN * FF / 4) / 256, 256, 0, stream>>>(x, xh, NN * FF / 4);
  k_convw<<<dim3(16, FF / 32, 4), dim3(32, 8), 0, stream>>>(W0q, W0k, W0v, W0s, FF, wt0);
  k_convw<<<dim3(16, 16, 28), dim3(32, 8), 0, stream>>>(Wq, Wk, Wv, Ws, DD, wtN);
  k_fbias<<<64, 256, 0, stream>>>(b0q, b0k, b0v, b0s, bq, bk, bv, bs, biasf);

  for (int layer = 0; layer < LL; ++layer) {
    int K = (layer == 0) ? FF : DD;
    const u16* A = (layer == 0) ? xh : hh;
    const u16* Bm = (layer == 0) ? wt0 : wtN + (size_t)(layer - 1) * 2048 * 512;
    k_gemm<<<dim3(16, 79), 256, 0, stream>>>(A, Bm, biasf + layer * 2048,
                                             qb16, kb16, vb16, sb, NN, K);
    k_attn<<<NN / 4, 256, 0, stream>>>(qb16, kb16, vb16, sb, offs, esrc);
    k_bnstat<<<dim3(2, 64), 256, 0, stream>>>(sb, bnpart);
    k_bnfinal<<<1, 512, 0, stream>>>(bnpart, gamma + layer * DD, beta + layer * DD,
                                     bnscale, bnshift);
    k_bnapply<<<(ND / 4) / 256, 256, 0, stream>>>(sb, bnscale, bnshift, hh);
    k_pool<<<dim3(2, 64), 256, 0, stream>>>(hh, bstart, out, layer);
  }
}

// Round 10
// 1386.382 us; speedup vs baseline: 2.7849x; 1.2449x over previous
//
#include <hip/hip_runtime.h>

#define NN 10000
#define EE 160000
#define FF 128
#define LL 8
#define BB 64
#define DD 512
#define ND (NN * DD)

typedef unsigned short u16;
typedef __attribute__((ext_vector_type(8))) short short8;
typedef __attribute__((ext_vector_type(8))) _Float16 f16x8;
typedef __attribute__((ext_vector_type(4))) float f32x4;
typedef __attribute__((ext_vector_type(4))) u16 u16x4;

__device__ __forceinline__ u16 f2h(float f) {
  return __builtin_bit_cast(u16, (_Float16)f);
}
__device__ __forceinline__ float h2f(u16 h) {
  return (float)__builtin_bit_cast(_Float16, h);
}
__device__ __forceinline__ void h8tof(short8 x, float* f) {
  f16x8 h = __builtin_bit_cast(f16x8, x);
#pragma unroll
  for (int j = 0; j < 8; ++j) f[j] = (float)h[j];
}

#define GLOAD_LDS16(gp, lp)                                                   \
  __builtin_amdgcn_global_load_lds(                                           \
      (const __attribute__((address_space(1))) void*)(gp),                    \
      (__attribute__((address_space(3))) void*)(lp), 16, 0, 0)

// ---------------- fp32 -> fp16 ----------------
__global__ void k_toh(const float* __restrict__ in, u16* __restrict__ out, int n4) {
  int i = blockIdx.x * 256 + threadIdx.x;
  if (i >= n4) return;
  float4 v = ((const float4*)in)[i];
  u16x4 h;
  h.x = f2h(v.x); h.y = f2h(v.y); h.z = f2h(v.z); h.w = f2h(v.w);
  ((u16x4*)out)[i] = h;
}

// ---------------- weight transpose+convert: W[lay][K][512] -> out[(lay*2048+mat*512+n)*K+k] fp16 ----------------
__global__ void k_convw(const float* __restrict__ W0, const float* __restrict__ W1,
                        const float* __restrict__ W2, const float* __restrict__ W3,
                        int K, u16* __restrict__ out) {
  __shared__ float t[32][33];
  int z = blockIdx.z;
  int lay = z >> 2, mat = z & 3;
  const float* W = ((mat == 0) ? W0 : (mat == 1) ? W1 : (mat == 2) ? W2 : W3) +
                   (size_t)lay * K * 512;
  int n0 = blockIdx.x * 32, k0 = blockIdx.y * 32;
  int tx = threadIdx.x, ty = threadIdx.y;
#pragma unroll
  for (int i = 0; i < 4; ++i)
    t[ty + 8 * i][tx] = W[(size_t)(k0 + ty + 8 * i) * 512 + n0 + tx];
  __syncthreads();
#pragma unroll
  for (int i = 0; i < 4; ++i) {
    int n = n0 + ty + 8 * i;
    float val = t[tx][ty + 8 * i];
    size_t o = ((size_t)lay * 2048 + mat * 512 + n) * K + k0 + tx;
    out[o] = f2h(val);
  }
}

// all-layer bias gather: biasf[l][2048]
__global__ void k_fbias(const float* __restrict__ b0q, const float* __restrict__ b0k,
                        const float* __restrict__ b0v, const float* __restrict__ b0s,
                        const float* __restrict__ bq, const float* __restrict__ bk,
                        const float* __restrict__ bv, const float* __restrict__ bs,
                        float* __restrict__ biasf) {
  int j = blockIdx.x * 256 + threadIdx.x;  // 0..16383
  int l = j >> 11, m = (j >> 9) & 3, c = j & 511;
  const float* p;
  if (l == 0) {
    p = (m == 0) ? b0q : (m == 1) ? b0k : (m == 2) ? b0v : b0s;
  } else {
    const float* base = (m == 0) ? bq : (m == 1) ? bk : (m == 2) ? bv : bs;
    p = base + (size_t)(l - 1) * 512;
  }
  biasf[j] = p[c];
}

// ---------------- fused q|k|v|s GEMM: 128x128 tile, 4 waves, BK=32, double-buffered ----------------
__global__ __launch_bounds__(256) void k_gemm(
    const u16* __restrict__ Ag, const u16* __restrict__ Bg,
    const float* __restrict__ biasf,
    u16* __restrict__ oq16, u16* __restrict__ ok16, u16* __restrict__ ov16,
    u16* __restrict__ os16, int M, int K) {
  __shared__ short8 sA[2][512], sB[2][512];
  const int tid = threadIdx.x;
  const int jt = blockIdx.x, mt = blockIdx.y;
  const int m0 = mt * 128;
  const int mat = jt >> 2;
  const int nbase = (jt & 3) * 128;
  const int K8 = K >> 3;
  const int l = tid & 63;
  const int wr = tid >> 7, wc = (tid >> 6) & 1;
  const int g = l >> 4, li = l & 15;

  const int c0 = tid, c1 = tid + 256;
  const int r0 = c0 >> 2, r1 = c1 >> 2;
  const int j0 = (c0 & 3) ^ (r0 & 3) ^ ((r0 >> 2) & 3);
  const int j1 = (c1 & 3) ^ (r1 & 3) ^ ((r1 >> 2) & 3);
  const int am0 = min(m0 + r0, M - 1), am1 = min(m0 + r1, M - 1);
  const int brow = mat * 512 + nbase;
  const short8* gA = (const short8*)Ag;
  const short8* gB = (const short8*)Bg;
  const size_t a0 = (size_t)am0 * K8 + j0, a1 = (size_t)am1 * K8 + j1;
  const size_t b0 = (size_t)(brow + r0) * K8 + j0, b1 = (size_t)(brow + r1) * K8 + j1;

  const f32x4 zero4 = {0.f, 0.f, 0.f, 0.f};
  f32x4 acc[4][4];
#pragma unroll
  for (int i = 0; i < 4; ++i)
#pragma unroll
    for (int j = 0; j < 4; ++j) acc[i][j] = zero4;

  auto stage = [&](int buf, int kg) {
    GLOAD_LDS16(gA + a0 + kg, &sA[buf][c0]);
    GLOAD_LDS16(gA + a1 + kg, &sA[buf][c1]);
    GLOAD_LDS16(gB + b0 + kg, &sB[buf][c0]);
    GLOAD_LDS16(gB + b1 + kg, &sB[buf][c1]);
  };

  auto compute = [&](int buf) {
    f16x8 fa[4], fb[4];
#pragma unroll
    for (int mi = 0; mi < 4; ++mi) {
      int row = wr * 64 + mi * 16 + li;
      int idx = row * 4 + (g ^ (row & 3) ^ ((row >> 2) & 3));
      fa[mi] = __builtin_bit_cast(f16x8, sA[buf][idx]);
    }
#pragma unroll
    for (int ni = 0; ni < 4; ++ni) {
      int row = wc * 64 + ni * 16 + li;
      int idx = row * 4 + (g ^ (row & 3) ^ ((row >> 2) & 3));
      fb[ni] = __builtin_bit_cast(f16x8, sB[buf][idx]);
    }
#pragma unroll
    for (int mi = 0; mi < 4; ++mi)
#pragma unroll
      for (int ni = 0; ni < 4; ++ni)
        acc[mi][ni] = __builtin_amdgcn_mfma_f32_16x16x32_f16(fa[mi], fb[ni], acc[mi][ni], 0, 0, 0);
  };

  int buf = 0;
  stage(0, 0);
  __syncthreads();
  for (int kg = 4; kg < K8; kg += 4) {
    stage(buf ^ 1, kg);
    compute(buf);
    __syncthreads();
    buf ^= 1;
  }
  compute(buf);

  u16* outp = (mat == 0) ? oq16 : (mat == 1) ? ok16 : (mat == 2) ? ov16 : os16;
#pragma unroll
  for (int mi = 0; mi < 4; ++mi) {
    int rbase = m0 + wr * 64 + mi * 16 + g * 4;
#pragma unroll
    for (int ni = 0; ni < 4; ++ni) {
      int col = nbase + wc * 64 + ni * 16 + li;
      float bv = biasf[(jt << 7) + wc * 64 + ni * 16 + li];
#pragma unroll
      for (int r = 0; r < 4; ++r) {
        int gm = rbase + r;
        if (gm < M) outp[(size_t)gm * 512 + col] = f2h(acc[mi][ni][r] + bv);
      }
    }
  }
}

// ---------------- CSR build ----------------
__global__ void k_count(const int* __restrict__ dst, int* __restrict__ counts) {
  int e = blockIdx.x * 256 + threadIdx.x;
  if (e < EE) atomicAdd(&counts[dst[e]], 1);
}

__global__ void k_scan(const int* __restrict__ counts, int* __restrict__ offs) {
  __shared__ int ws[1024];
  int t = threadIdx.x;
  int base = t * 10;
  int loc[10];
  int run = 0;
#pragma unroll
  for (int j = 0; j < 10; ++j) {
    int i = base + j;
    int v = (i < NN) ? counts[i] : 0;
    run += v;
    loc[j] = run;
  }
  ws[t] = run;
  __syncthreads();
  for (int d = 1; d < 1024; d <<= 1) {
    int x = (t >= d) ? ws[t - d] : 0;
    __syncthreads();
    ws[t] += x;
    __syncthreads();
  }
  int pre = (t > 0) ? ws[t - 1] : 0;
#pragma unroll
  for (int j = 0; j < 10; ++j) {
    int i = base + j;
    if (i < NN) offs[i + 1] = pre + loc[j];
  }
  if (t == 0) offs[0] = 0;
}

__global__ void k_scatter(const int* __restrict__ src, const int* __restrict__ dst,
                          const int* __restrict__ offs, int* __restrict__ cursor,
                          int* __restrict__ esrc) {
  int e = blockIdx.x * 256 + threadIdx.x;
  if (e < EE) {
    int d = dst[e];
    int pos = offs[d] + atomicAdd(&cursor[d], 1);
    esrc[pos] = src[e];
  }
}

__global__ void k_bstart(const int* __restrict__ batch, int* __restrict__ bstart) {
  int n = blockIdx.x * 256 + threadIdx.x;
  if (n > NN) return;
  if (n == 0) {
    for (int b = 0; b <= batch[0]; ++b) bstart[b] = 0;
  } else if (n == NN) {
    for (int b = batch[NN - 1] + 1; b <= BB; ++b) bstart[b] = NN;
  } else {
    int bp = batch[n - 1], bn = batch[n];
    for (int b = bp + 1; b <= bn; ++b) bstart[b] = n;
  }
}

// ---------------- per-node flash attention (fp16 q/k/v/s, unroll-4) ----------------
__global__ __launch_bounds__(256) void k_attn(
    const u16* __restrict__ q16, const u16* __restrict__ k16,
    const u16* __restrict__ v16, u16* __restrict__ s16,
    const int* __restrict__ offs, const int* __restrict__ esrc) {
  int node = blockIdx.x * 4 + (threadIdx.x >> 6);
  int l = threadIdx.x & 63;
  const short8* qp = (const short8*)q16;
  float qf[8];
  h8tof(qp[(size_t)node * 64 + l], qf);
  const short8* kp = (const short8*)k16;
  const short8* vp = (const short8*)v16;
  float m = -3.4e38f, ssum = 0.f;
  float a[8] = {0.f, 0.f, 0.f, 0.f, 0.f, 0.f, 0.f, 0.f};
  int e0 = offs[node], e1 = offs[node + 1];
  int e = e0;
  for (; e + 4 <= e1; e += 4) {
    int sn0 = esrc[e], sn1 = esrc[e + 1], sn2 = esrc[e + 2], sn3 = esrc[e + 3];
    short8 kk0 = kp[(size_t)sn0 * 64 + l];
    short8 kk1 = kp[(size_t)sn1 * 64 + l];
    short8 kk2 = kp[(size_t)sn2 * 64 + l];
    short8 kk3 = kp[(size_t)sn3 * 64 + l];
    short8 vv0 = vp[(size_t)sn0 * 64 + l];
    short8 vv1 = vp[(size_t)sn1 * 64 + l];
    short8 vv2 = vp[(size_t)sn2 * 64 + l];
    short8 vv3 = vp[(size_t)sn3 * 64 + l];
    float kf0[8], kf1[8], kf2[8], kf3[8];
    h8tof(kk0, kf0); h8tof(kk1, kf1); h8tof(kk2, kf2); h8tof(kk3, kf3);
    float d0 = 0.f, d1 = 0.f, d2 = 0.f, d3 = 0.f;
#pragma unroll
    for (int j = 0; j < 8; ++j) {
      d0 += qf[j] * kf0[j]; d1 += qf[j] * kf1[j];
      d2 += qf[j] * kf2[j]; d3 += qf[j] * kf3[j];
    }
    d0 += __shfl_xor(d0, 1); d1 += __shfl_xor(d1, 1);
    d2 += __shfl_xor(d2, 1); d3 += __shfl_xor(d3, 1);
    d0 += __shfl_xor(d0, 2); d1 += __shfl_xor(d1, 2);
    d2 += __shfl_xor(d2, 2); d3 += __shfl_xor(d3, 2);
    d0 += __shfl_xor(d0, 4); d1 += __shfl_xor(d1, 4);
    d2 += __shfl_xor(d2, 4); d3 += __shfl_xor(d3, 4);
    float vf0[8], vf1[8], vf2[8], vf3[8];
    h8tof(vv0, vf0); h8tof(vv1, vf1); h8tof(vv2, vf2); h8tof(vv3, vf3);
    {
      float logit = d0 * 0.125f;
      float mn = fmaxf(m, logit);
      float sc = __expf(m - mn), p = __expf(logit - mn);
      ssum = ssum * sc + p;
#pragma unroll
      for (int j = 0; j < 8; ++j) a[j] = a[j] * sc + p * vf0[j];
      m = mn;
    }
    {
      float logit = d1 * 0.125f;
      float mn = fmaxf(m, logit);
      float sc = __expf(m - mn), p = __expf(logit - mn);
      ssum = ssum * sc + p;
#pragma unroll
      for (int j = 0; j < 8; ++j) a[j] = a[j] * sc + p * vf1[j];
      m = mn;
    }
    {
      float logit = d2 * 0.125f;
      float mn = fmaxf(m, logit);
      float sc = __expf(m - mn), p = __expf(logit - mn);
      ssum = ssum * sc + p;
#pragma unroll
      for (int j = 0; j < 8; ++j) a[j] = a[j] * sc + p * vf2[j];
      m = mn;
    }
    {
      float logit = d3 * 0.125f;
      float mn = fmaxf(m, logit);
      float sc = __expf(m - mn), p = __expf(logit - mn);
      ssum = ssum * sc + p;
#pragma unroll
      for (int j = 0; j < 8; ++j) a[j] = a[j] * sc + p * vf3[j];
      m = mn;
    }
  }
  for (; e < e1; ++e) {
    int sn0 = esrc[e];
    short8 kk0 = kp[(size_t)sn0 * 64 + l];
    short8 vv0 = vp[(size_t)sn0 * 64 + l];
    float kf0[8], vf0[8];
    h8tof(kk0, kf0);
    h8tof(vv0, vf0);
    float d0 = 0.f;
#pragma unroll
    for (int j = 0; j < 8; ++j) d0 += qf[j] * kf0[j];
    d0 += __shfl_xor(d0, 1);
    d0 += __shfl_xor(d0, 2);
    d0 += __shfl_xor(d0, 4);
    float logit = d0 * 0.125f;
    float mn = fmaxf(m, logit);
    float sc = __expf(m - mn), p = __expf(logit - mn);
    ssum = ssum * sc + p;
#pragma unroll
    for (int j = 0; j < 8; ++j) a[j] = a[j] * sc + p * vf0[j];
    m = mn;
  }
  float inv = (e1 > e0) ? 1.f / (ssum + 1e-16f) : 0.f;
  short8* sp = (short8*)s16;
  short8 srow = sp[(size_t)node * 64 + l];
  float sf[8];
  h8tof(srow, sf);
  short8 hout;
#pragma unroll
  for (int j = 0; j < 8; ++j) hout[j] = (short)f2h(sf[j] + a[j] * inv);
  sp[(size_t)node * 64 + l] = hout;
}

// ---------------- BN partial stats: 64 blocks, short8 loads -> bnpart[64][1024] ----------------
__global__ __launch_bounds__(256) void k_bnstat(const u16* __restrict__ s16,
                                                float* __restrict__ bnpart) {
  __shared__ float red[256][8];
  int tid = threadIdx.x, blk = blockIdx.x;  // 64 blocks
  int g = tid & 63;                          // channel group (8 ch)
  int w = blk * 4 + (tid >> 6);              // walker 0..255
  float sum[8] = {0, 0, 0, 0, 0, 0, 0, 0};
  float sq[8] = {0, 0, 0, 0, 0, 0, 0, 0};
  const short8* sp = (const short8*)s16;
  for (int r = w; r < NN; r += 256) {
    float f[8];
    h8tof(sp[(size_t)r * 64 + g], f);
#pragma unroll
    for (int j = 0; j < 8; ++j) { sum[j] += f[j]; sq[j] += f[j] * f[j]; }
  }
#pragma unroll
  for (int j = 0; j < 8; ++j) red[tid][j] = sum[j];
  __syncthreads();
  if (tid < 64) {
#pragma unroll
    for (int j = 0; j < 8; ++j) {
      float t = red[tid][j] + red[tid + 64][j] + red[tid + 128][j] + red[tid + 192][j];
      bnpart[blk * 1024 + tid * 8 + j] = t;
    }
  }
  __syncthreads();
#pragma unroll
  for (int j = 0; j < 8; ++j) red[tid][j] = sq[j];
  __syncthreads();
  if (tid < 64) {
#pragma unroll
    for (int j = 0; j < 8; ++j) {
      float t = red[tid][j] + red[tid + 64][j] + red[tid + 128][j] + red[tid + 192][j];
      bnpart[blk * 1024 + 512 + tid * 8 + j] = t;
    }
  }
}

// ---------------- BN apply (finalize folded in) + ReLU -> fp16 hh ----------------
__global__ __launch_bounds__(256) void k_bnapply(
    const u16* __restrict__ s16, const float* __restrict__ bnpart,
    const float* __restrict__ gamma, const float* __restrict__ beta,
    u16* __restrict__ hh) {
  __shared__ float ssc[1024];
  int tid = threadIdx.x;
  for (int c = tid; c < 512; c += 256) {
    float sum = 0.f, sq = 0.f;
    for (int p = 0; p < 64; ++p) {
      sum += bnpart[p * 1024 + c];
      sq += bnpart[p * 1024 + 512 + c];
    }
    float mu = sum * (1.f / NN);
    float var = sq * (1.f / NN) - mu * mu;
    float inv = rsqrtf(var + 1e-5f);
    float scl = gamma[c] * inv;
    ssc[c] = scl;
    ssc[512 + c] = beta[c] - mu * scl;
  }
  __syncthreads();
  const short8* sp = (const short8*)s16;
  short8* hp = (short8*)hh;
  int total = gridDim.x * 256;
  for (int j = blockIdx.x * 256 + tid; j < ND / 8; j += total) {
    int c0 = (j & 63) * 8;
    float f[8];
    h8tof(sp[j], f);
    short8 h;
#pragma unroll
    for (int jj = 0; jj < 8; ++jj)
      h[jj] = (short)f2h(fmaxf(f[jj] * ssc[c0 + jj] + ssc[512 + c0 + jj], 0.f));
    hp[j] = h;
  }
}

// ---------------- pool from fp16 hh ----------------
__global__ void k_pool(const u16* __restrict__ hh, const int* __restrict__ bstart,
                       float* __restrict__ out, int layer) {
  int c = blockIdx.x * 256 + threadIdx.x;
  int b = blockIdx.y;
  int r0 = bstart[b], r1 = bstart[b + 1];
  float sum = 0.f;
  for (int r = r0; r < r1; ++r) sum += h2f(hh[(size_t)r * 512 + c]);
  out[(size_t)b * 4096 + layer * 512 + c] = sum / fmaxf((float)(r1 - r0), 1.f);
}

// ---------------- host ----------------
extern "C" void kernel_launch(void* const* d_in, const int* in_sizes, int n_in,
                              void* d_out, int out_size, void* d_ws, size_t ws_size,
                              hipStream_t stream) {
  (void)in_sizes; (void)n_in; (void)out_size; (void)ws_size;
  const float* x = (const float*)d_in[0];
  const int* ei = (const int*)d_in[1];
  const int* src = ei;
  const int* dst = ei + EE;
  const int* batch = (const int*)d_in[2];
  const float* W0q = (const float*)d_in[3];
  const float* b0q = (const float*)d_in[4];
  const float* W0k = (const float*)d_in[5];
  const float* b0k = (const float*)d_in[6];
  const float* W0v = (const float*)d_in[7];
  const float* b0v = (const float*)d_in[8];
  const float* W0s = (const float*)d_in[9];
  const float* b0s = (const float*)d_in[10];
  const float* Wq = (const float*)d_in[11];
  const float* bq = (const float*)d_in[12];
  const float* Wk = (const float*)d_in[13];
  const float* bk = (const float*)d_in[14];
  const float* Wv = (const float*)d_in[15];
  const float* bv = (const float*)d_in[16];
  const float* Ws = (const float*)d_in[17];
  const float* bs = (const float*)d_in[18];
  const float* gamma = (const float*)d_in[19];
  const float* beta = (const float*)d_in[20];
  float* out = (float*)d_out;

  char* w = (char*)d_ws;
  size_t off = 0;
  auto alloc = [&](size_t bytes) -> void* {
    void* p = w + off;
    off = (off + bytes + 255) & ~(size_t)255;
    return p;
  };
  u16* xh = (u16*)alloc((size_t)NN * FF * 2);
  u16* hh = (u16*)alloc((size_t)ND * 2);
  u16* qb16 = (u16*)alloc((size_t)ND * 2);
  u16* kb16 = (u16*)alloc((size_t)ND * 2);
  u16* vb16 = (u16*)alloc((size_t)ND * 2);
  u16* sb16 = (u16*)alloc((size_t)ND * 2);
  u16* wt0 = (u16*)alloc((size_t)4 * 512 * FF * 2);
  u16* wtN = (u16*)alloc((size_t)7 * 4 * 512 * 512 * 2);
  float* biasf = (float*)alloc((size_t)LL * 2048 * 4);
  float* bnpart = (float*)alloc((size_t)64 * 1024 * 4);
  int* counts = (int*)alloc(NN * 4);
  int* offs = (int*)alloc((NN + 1) * 4);
  int* cursor = (int*)alloc(NN * 4);
  int* esrc = (int*)alloc(EE * 4);
  int* bstart = (int*)alloc((BB + 1) * 4);

  // ---- once-per-launch setup ----
  hipMemsetAsync(counts, 0, NN * 4, stream);
  hipMemsetAsync(cursor, 0, NN * 4, stream);
  k_count<<<EE / 256, 256, 0, stream>>>(dst, counts);
  k_scan<<<1, 1024, 0, stream>>>(counts, offs);
  k_scatter<<<EE / 256, 256, 0, stream>>>(src, dst, offs, cursor, esrc);
  k_bstart<<<(NN + 256) / 256, 256, 0, stream>>>(batch, bstart);
  k_toh<<<(NN * FF / 4) / 256, 256, 0, stream>>>(x, xh, NN * FF / 4);
  k_convw<<<dim3(16, FF / 32, 4), dim3(32, 8), 0, stream>>>(W0q, W0k, W0v, W0s, FF, wt0);
  k_convw<<<dim3(16, 16, 28), dim3(32, 8), 0, stream>>>(Wq, Wk, Wv, Ws, DD, wtN);
  k_fbias<<<64, 256, 0, stream>>>(b0q, b0k, b0v, b0s, bq, bk, bv, bs, biasf);

  for (int layer = 0; layer < LL; ++layer) {
    int K = (layer == 0) ? FF : DD;
    const u16* A = (layer == 0) ? xh : hh;
    const u16* Bm = (layer == 0) ? wt0 : wtN + (size_t)(layer - 1) * 2048 * 512;
    k_gemm<<<dim3(16, 79), 256, 0, stream>>>(A, Bm, biasf + layer * 2048,
                                             qb16, kb16, vb16, sb16, NN, K);
    k_attn<<<NN / 4, 256, 0, stream>>>(qb16, kb16, vb16, sb16, offs, esrc);
    k_bnstat<<<64, 256, 0, stream>>>(sb16, bnpart);
    k_bnapply<<<320, 256, 0, stream>>>(sb16, bnpart, gamma + layer * DD,
                                       beta + layer * DD, hh);
    k_pool<<<dim3(2, 64), 256, 0, stream>>>(hh, bstart, out, layer);
  }
}